// Round 3
// baseline (1359.916 us; speedup 1.0000x reference)
//
#include <hip/hip_runtime.h>
#include <stdint.h>

// SNN forward (Mozafari 2018), max_layer==2:
//   pad(2) -> conv1(30,6,5,5) -> fire(>15) -> maxpool2x2 -> pad(1)
//   -> conv2(240,30,3,3) -> fire(>10) -> out = spk ++ pot (f32)
//
// f16 MFMA implicit GEMM (structure unchanged from round-1/2; see comments
// on each kernel).
//
// DIAGNOSTIC THIS ROUND: in-kernel idempotent repeats (conv1 x16, conv2 x4)
// so both kernels exceed the ~228us poison fills and surface in the top-5
// PMC table with their own WRITE_SIZE / FETCH_SIZE / MfmaUtil / VALUBusy.
//   c1 = dur(conv1_mfma)/16, c2 = dur(conv2_mfma)/4.
// Decision variable: conv2 WRITE_SIZE ~1.44 GB (clean writes, near floor)
// vs >=2.5 GB (partial-line write amplification -> LDS-transpose epilogue
// next round). Repeats write identical bytes -> passed/absmax unchanged.

typedef _Float16 half8  __attribute__((ext_vector_type(8)));
typedef _Float16 half8u __attribute__((ext_vector_type(8), aligned(4)));
typedef float f32x4  __attribute__((ext_vector_type(4)));

#define POT1_T 15.0f
#define POT2_T 10.0f

#define C1_REP 16
#define C2_REP 4

// ---- ws layout (all 16B aligned) ----
#define SPK_ELEMS  (15*114*114*32)            // 6,238,080 f16 (ch-interleaved, padded)
#define SPK_BYTES  (SPK_ELEMS*2)              // 12,476,160
#define BP2_OFF    SPK_BYTES
#define BP2_BYTES  (9*15*64*8*2)              // 138,240
#define BP1_OFF    (BP2_OFF + BP2_BYTES)
#define BP1_BYTES  (8*2*64*8*2)               // 16,384
#define IN16_OFF   (BP1_OFF + BP1_BYTES)      // 12,630,784 (16B aligned)
#define IN16_ELEMS (90*228*228)               // 4,678,560 f16 per copy

#define PAD_BLOCKS ((IN16_ELEMS + 255) / 256) // 18276

#define RING_UINT4  (15 * 452 * 4)            // 27120
#define RING_BLOCKS ((RING_UINT4 + 255) / 256)

__device__ __forceinline__ unsigned short f2h(float v) {
  union { _Float16 h; unsigned short u; } c;
  c.h = (_Float16)v;                          // RNE
  return c.u;
}

// ---------------------------------------------------------------------------
// prep: pad input -> f16, dual copies (ina[i]=v(i), inb[i-1]=v(i)), weight
// packing to MFMA B-frag layout [step][nsub][lane][8], and spike-map pad-ring
// zeroing (replaces a 12.5 MB memset).
// ---------------------------------------------------------------------------
__global__ __launch_bounds__(256) void prep(
    const float* __restrict__ in, const float* __restrict__ w1,
    const float* __restrict__ w2, unsigned short* __restrict__ ina,
    unsigned short* __restrict__ bp2, unsigned short* __restrict__ bp1,
    unsigned short* __restrict__ spk16)
{
  const int blk = blockIdx.x;
  if (blk < PAD_BLOCKS) {
    const int i = blk * 256 + threadIdx.x;
    if (i >= IN16_ELEMS) return;
    const int xx = i % 228, t = i / 228;
    const int yy = t % 228, c = t / 228;
    const int xi = xx - 2, yi = yy - 2;
    float v = 0.0f;
    if ((unsigned)xi < 224u && (unsigned)yi < 224u)
      v = in[(c * 224 + yi) * 224 + xi];
    const unsigned short h = f2h(v);
    unsigned short* inb = ina + IN16_ELEMS;
    ina[i] = h;
    if (i > 0) inb[i - 1] = h;
    if (i == IN16_ELEMS - 1) inb[i] = 0;
    return;
  }
  const int b = blk - PAD_BLOCKS;              // 0..150 weights, 151.. ring
  if (b >= 151) {                              // ---- pad-ring zero ----
    const int idx = (b - 151) * 256 + threadIdx.x;
    if (idx >= RING_UINT4) return;
    const int part = idx & 3, cell = idx >> 2;
    const int n = cell / 452, rp = cell - n * 452;
    int y, x;
    if (rp < 114)      { y = 0;   x = rp; }
    else if (rp < 228) { y = 113; x = rp - 114; }
    else {
      const int r2 = rp - 228;                 // 0..223
      x = (r2 & 1) ? 113 : 0;
      y = 1 + (r2 >> 1);                       // 1..112
    }
    const int off = ((n * 114 + y) * 114 + x) * 32 + part * 8;
    *(uint4*)(spk16 + off) = (uint4){0u, 0u, 0u, 0u};
    return;
  }
  if (threadIdx.x >= 64) return;
  const int lane = threadIdx.x;
  const int quad = lane >> 4, nl = lane & 15;
  if (b < 135) {                               // conv2: 9 steps x 15 nsub
    const int s = b / 15, nsub = b - s * 15;   // s = ky*3+kx
    const int ch = nsub * 16 + nl;
    unsigned short* dst = bp2 + (((s * 15 + nsub) * 64 + lane) << 3);
    #pragma unroll
    for (int j = 0; j < 8; ++j) {
      const int ci = quad * 8 + j;
      dst[j] = f2h((ci < 30) ? w2[ch * 270 + ci * 9 + s] : 0.0f);
    }
  } else {                                     // conv1: 8 steps x 2 nsub
    const int bb = b - 135;
    const int s = bb >> 1, nsub = bb & 1;
    const int ch = nsub * 16 + nl;
    unsigned short* dst = bp1 + (((s * 2 + nsub) * 64 + lane) << 3);
    #pragma unroll
    for (int j = 0; j < 8; ++j) {
      int ci, ky;
      bool ok = (ch < 30) && (j < 5);
      if (s < 6)       { ci = s;        ky = quad; }
      else if (s == 6) { ci = quad;     ky = 4;    }
      else             { ci = 4 + quad; ky = 4; ok = ok && (quad < 2); }
      float v = 0.0f;
      if (ok) v = w1[ch * 150 + ci * 25 + ky * 5 + j];
      dst[j] = f2h(v);
    }
  }
}

// ---------------------------------------------------------------------------
// conv1 + fire + maxpool2x2. Pool-interleaved M. M=64/wave. A-frag = one
// 4B-aligned b128 from the parity-matched input copy. grid 2940 x 256.
// Chunked-XCD swizzle (bijective, q=367 r=4). DIAG: x C1_REP idempotent.
// ---------------------------------------------------------------------------
__global__ __launch_bounds__(256) void conv1_mfma(
    const unsigned short* __restrict__ in16,   // ina; inb = ina + IN16_ELEMS
    const unsigned short* __restrict__ bp1,
    unsigned short* __restrict__ spk16)
{
  const int tid = threadIdx.x;
  const int wave = tid >> 6, lane = tid & 63;
  const int quad = lane >> 4, nl = lane & 15;

  // bijective chunked XCD swizzle of 2940 blocks: q=367, r=4
  const int bid = blockIdx.x;
  const int xcd = bid & 7, pos = bid >> 3;
  const int sb = (xcd < 4) ? (xcd * 368 + pos)
                           : (4 * 368 + (xcd - 4) * 367 + pos);
  const int m0 = sb * 256 + wave * 64;

  // parity of x0 is lane-constant: p = nl & 1 (m0, c*16 even)
  const unsigned short* base = in16 + ((nl & 1) ? (IN16_ELEMS - 1) : 0);

  unsigned o_q[4], o_a[4], o_b[4];
  #pragma unroll
  for (int c = 0; c < 4; ++c) {
    const int m = m0 + c * 16 + nl;
    const int sub = m & 3, g = m >> 2;
    const int gx = g % 112, t = g / 112;
    const int gy = t % 112, n = t / 112;
    const int y0 = gy * 2 + (sub >> 1);        // padded coords
    const int x0 = gx * 2 + (sub & 1);
    const unsigned nb = (unsigned)n * 311904u; // 6*51984
    o_q[c] = nb + (unsigned)((y0 + quad) * 228 + x0);
    o_a[c] = nb + (unsigned)quad * 51984u + (unsigned)((y0 + 4) * 228 + x0);
    o_b[c] = nb + (unsigned)(4 + (quad & 1)) * 51984u + (unsigned)((y0 + 4) * 228 + x0);
  }

  const half8* bptr = (const half8*)bp1;

  #pragma unroll 1
  for (int rep = 0; rep < C1_REP; ++rep) {
    f32x4 acc[4][2];
    #pragma unroll
    for (int c = 0; c < 4; ++c) {
      acc[c][0] = (f32x4){0.f, 0.f, 0.f, 0.f};
      acc[c][1] = (f32x4){0.f, 0.f, 0.f, 0.f};
    }

    #pragma unroll
    for (int s = 0; s < 8; ++s) {
      const half8 b0 = bptr[(s * 2 + 0) * 64 + lane];
      const half8 b1 = bptr[(s * 2 + 1) * 64 + lane];
      #pragma unroll
      for (int c = 0; c < 4; ++c) {
        const unsigned off = (s < 6) ? (o_q[c] + (unsigned)s * 51984u)
                                     : (s == 6 ? o_a[c] : o_b[c]);
        const half8 A = *(const half8u*)(base + off);
        acc[c][0] = __builtin_amdgcn_mfma_f32_16x16x32_f16(A, b0, acc[c][0], 0, 0, 0);
        acc[c][1] = __builtin_amdgcn_mfma_f32_16x16x32_f16(A, b1, acc[c][1], 0, 0, 0);
      }
    }

    #pragma unroll
    for (int c = 0; c < 4; ++c) {
      const int gq = ((m0 + c * 16) >> 2) + quad;
      const int pgx = gq % 112, tq = gq / 112;
      const int pgy = tq % 112, nq = tq / 112;
      const bool f0 = (acc[c][0][0] > POT1_T) | (acc[c][0][1] > POT1_T) |
                      (acc[c][0][2] > POT1_T) | (acc[c][0][3] > POT1_T);
      const bool f1 = (acc[c][1][0] > POT1_T) | (acc[c][1][1] > POT1_T) |
                      (acc[c][1][2] > POT1_T) | (acc[c][1][3] > POT1_T);
      const size_t o = ((size_t)(nq * 114 + pgy + 1) * 114 + (pgx + 1)) * 32 + nl;
      spk16[o] = f0 ? (unsigned short)0x3C00 : (unsigned short)0;
      // ch>=30 weights are zero-packed -> acc==0 -> stores 0 (inits ch 30/31)
      spk16[o + 16] = f1 ? (unsigned short)0x3C00 : (unsigned short)0;
    }
  }
}

// ---------------------------------------------------------------------------
// conv2 + fire: block = 4 waves x M=64 = 256 rows; N = 5 subtiles (80 ch),
// 3 N-tiles cover 240. B staged in LDS (46 KB). Subtiles in two groups
// (3 then 2) so group-0 stores overlap group-1 compute. grid 2208 x 256,
// sibling-XCD swizzle. DIAG: x C2_REP idempotent.
// ---------------------------------------------------------------------------
#define C2_NSUB 5
__global__ __launch_bounds__(256, 3) void conv2_mfma(
    const unsigned short* __restrict__ spk16,
    const unsigned short* __restrict__ bp2,
    float* __restrict__ out_spk, float* __restrict__ out_pot)
{
  __shared__ __attribute__((aligned(16))) unsigned short Blds[C2_NSUB * 9 * 64 * 8];

  const int tid = threadIdx.x;

  // sibling-XCD swizzle: gid -> (bx, ntile); 3 siblings of one A region
  // land on the same XCD (gid % 8 equal) within a 24-id window.
  const int gid = blockIdx.x;                  // 0..2207
  const int v = gid / 24, u = gid - v * 24;
  const int bx = v * 8 + (u & 7);              // 0..735
  const int ntile = u >> 3;                    // 0..2
  if (bx >= 735) return;                       // 3 idle blocks (uniform exit)

  // stage 5 subtiles x 9 steps x 64 lanes x 16B = 2880 uint4
  for (int i = tid; i < 2880; i += 256) {
    const int su = i / 576, rem = i - su * 576;    // rem = s*64+lane
    ((uint4*)Blds)[su * 576 + rem] =
        ((const uint4*)bp2)[((rem >> 6) * 15 + ntile * C2_NSUB + su) * 64 + (rem & 63)];
  }
  __syncthreads();

  const int wave = tid >> 6, lane = tid & 63;
  const int quad = lane >> 4, nl = lane & 15;
  const int m0 = bx * 256 + wave * 64;

  const unsigned short* abase[4];
  #pragma unroll
  for (int c = 0; c < 4; ++c) {
    const int m = m0 + c * 16 + nl;
    const int x = m % 112, t = m / 112;
    const int y = t % 112, n = t / 112;
    abase[c] = spk16 + ((size_t)(n * 114 + y) * 114 + x) * 32 + quad * 8;
  }

  const half8* blds = (const half8*)Blds;

  #pragma unroll 1
  for (int rep = 0; rep < C2_REP; ++rep) {
    #pragma unroll
    for (int g = 0; g < 2; ++g) {
      const int ub = g ? 3 : 0;                // subtile base of this group
      const int uc = g ? 2 : 3;                // subtiles in this group

      f32x4 acc[4][3];
      #pragma unroll
      for (int c = 0; c < 4; ++c)
        #pragma unroll
        for (int u2 = 0; u2 < 3; ++u2) acc[c][u2] = (f32x4){0.f, 0.f, 0.f, 0.f};

      #pragma unroll
      for (int s = 0; s < 9; ++s) {            // s = ky*3+kx
        const int ky = s / 3, kx = s - ky * 3; // compile-time under unroll
        half8 a[4];
        #pragma unroll
        for (int c = 0; c < 4; ++c)
          a[c] = *(const half8*)(abase[c] + (ky * 114 + kx) * 32);
        #pragma unroll
        for (int u2 = 0; u2 < 3; ++u2) {
          if (u2 < uc) {
            const half8 b = blds[((ub + u2) * 9 + s) * 64 + lane];
            #pragma unroll
            for (int c = 0; c < 4; ++c)
              acc[c][u2] = __builtin_amdgcn_mfma_f32_16x16x32_f16(a[c], b, acc[c][u2], 0, 0, 0);
          }
        }
      }

      // epilogue for this group: chunk c rows mrow..mrow+3 contiguous in x
      #pragma unroll
      for (int c = 0; c < 4; ++c) {
        const int mrow = m0 + c * 16 + quad * 4;
        const int xr = mrow % 112, tr = mrow / 112;
        const int yr = tr % 112, nr = tr / 112;
        #pragma unroll
        for (int u2 = 0; u2 < 3; ++u2) {
          if (u2 < uc) {
            const int ch = (ntile * C2_NSUB + ub + u2) * 16 + nl;
            const size_t o = ((size_t)(nr * 240 + ch) * 112 + yr) * 112 + xr;
            f32x4 sp, pt;
            #pragma unroll
            for (int rr = 0; rr < 4; ++rr) {
              const float p = acc[c][u2][rr];
              const bool f = p > POT2_T;
              sp[rr] = f ? 1.0f : 0.0f;
              pt[rr] = f ? p : 0.0f;
            }
            __builtin_nontemporal_store(sp, (f32x4*)(out_spk + o));
            __builtin_nontemporal_store(pt, (f32x4*)(out_pot + o));
          }
        }
      }
      // keep group phases separate so group-0 stores overlap group-1 compute
      __builtin_amdgcn_sched_barrier(0);
    }
  }
}

// ---------------------------------------------------------------------------
extern "C" void kernel_launch(void* const* d_in, const int* in_sizes, int n_in,
                              void* d_out, int out_size, void* d_ws, size_t ws_size,
                              hipStream_t stream)
{
  const float* in = (const float*)d_in[0];
  const float* w1 = (const float*)d_in[1];
  const float* w2 = (const float*)d_in[2];
  float* out = (float*)d_out;

  unsigned short* spk16 = (unsigned short*)d_ws;
  unsigned short* bp2   = (unsigned short*)((char*)d_ws + BP2_OFF);
  unsigned short* bp1   = (unsigned short*)((char*)d_ws + BP1_OFF);
  unsigned short* ina   = (unsigned short*)((char*)d_ws + IN16_OFF);

  prep<<<PAD_BLOCKS + 151 + RING_BLOCKS, 256, 0, stream>>>(
      in, w1, w2, ina, bp2, bp1, spk16);
  conv1_mfma<<<2940, 256, 0, stream>>>(ina, bp1, spk16);
  conv2_mfma<<<2208, 256, 0, stream>>>(
      spk16, bp2, out, out + (size_t)15 * 240 * 112 * 112);
}

// Round 4
// 426.505 us; speedup vs baseline: 3.1885x; 3.1885x over previous
//
#include <hip/hip_runtime.h>
#include <stdint.h>

// SNN forward (Mozafari 2018), max_layer==2:
//   pad(2) -> conv1(30,6,5,5) -> fire(>15) -> maxpool2x2 -> pad(1)
//   -> conv2(240,30,3,3) -> fire(>10) -> out = spk ++ pot (f32)
//
// f16 MFMA implicit GEMM.
//  conv1: step s -> (ci,ky), quad -> row, j -> kx. K=256. Dual f16 input
//         copies for 4B-aligned b128 A-loads. M=64/wave. ~14us (r3 diag).
//  conv2: K=288 (ch-interleaved spike map). B staged in LDS. NEW (r4):
//         LDS-transpose epilogue — r3 PMCs showed 497MB WRITE (1.38x) +
//         202MB FETCH (13x): 64B partial-line nt stores failed to merge in
//         TCC -> RMW fills + double write-back. Per wave the 64 m-positions
//         are flat-contiguous (256B aligned; 12544=196*64 so no n-crossing),
//         so bounce potentials through 4KB/wave LDS (16B-granule XOR
//         swizzle, conflict-floor both sides) and store 1KB/instr = 4 ch x
//         256B of FULL aligned lines. sp/pt derived after reload (bounce
//         only pot). Predicted c2 230 -> ~90us.

typedef _Float16 half8  __attribute__((ext_vector_type(8)));
typedef _Float16 half8u __attribute__((ext_vector_type(8), aligned(4)));
typedef float f32x4  __attribute__((ext_vector_type(4)));

#define POT1_T 15.0f
#define POT2_T 10.0f

// ---- ws layout (all 16B aligned) ----
#define SPK_ELEMS  (15*114*114*32)            // 6,238,080 f16 (ch-interleaved, padded)
#define SPK_BYTES  (SPK_ELEMS*2)              // 12,476,160
#define BP2_OFF    SPK_BYTES
#define BP2_BYTES  (9*15*64*8*2)              // 138,240
#define BP1_OFF    (BP2_OFF + BP2_BYTES)
#define BP1_BYTES  (8*2*64*8*2)               // 16,384
#define IN16_OFF   (BP1_OFF + BP1_BYTES)      // 12,630,784 (16B aligned)
#define IN16_ELEMS (90*228*228)               // 4,678,560 f16 per copy

#define PAD_BLOCKS ((IN16_ELEMS + 255) / 256) // 18276

#define RING_UINT4  (15 * 452 * 4)            // 27120
#define RING_BLOCKS ((RING_UINT4 + 255) / 256)

__device__ __forceinline__ unsigned short f2h(float v) {
  union { _Float16 h; unsigned short u; } c;
  c.h = (_Float16)v;                          // RNE
  return c.u;
}

// ---------------------------------------------------------------------------
// prep: pad input -> f16, dual copies (ina[i]=v(i), inb[i-1]=v(i)), weight
// packing to MFMA B-frag layout [step][nsub][lane][8], and spike-map pad-ring
// zeroing (replaces a 12.5 MB memset).
// ---------------------------------------------------------------------------
__global__ __launch_bounds__(256) void prep(
    const float* __restrict__ in, const float* __restrict__ w1,
    const float* __restrict__ w2, unsigned short* __restrict__ ina,
    unsigned short* __restrict__ bp2, unsigned short* __restrict__ bp1,
    unsigned short* __restrict__ spk16)
{
  const int blk = blockIdx.x;
  if (blk < PAD_BLOCKS) {
    const int i = blk * 256 + threadIdx.x;
    if (i >= IN16_ELEMS) return;
    const int xx = i % 228, t = i / 228;
    const int yy = t % 228, c = t / 228;
    const int xi = xx - 2, yi = yy - 2;
    float v = 0.0f;
    if ((unsigned)xi < 224u && (unsigned)yi < 224u)
      v = in[(c * 224 + yi) * 224 + xi];
    const unsigned short h = f2h(v);
    unsigned short* inb = ina + IN16_ELEMS;
    ina[i] = h;
    if (i > 0) inb[i - 1] = h;
    if (i == IN16_ELEMS - 1) inb[i] = 0;
    return;
  }
  const int b = blk - PAD_BLOCKS;              // 0..150 weights, 151.. ring
  if (b >= 151) {                              // ---- pad-ring zero ----
    const int idx = (b - 151) * 256 + threadIdx.x;
    if (idx >= RING_UINT4) return;
    const int part = idx & 3, cell = idx >> 2;
    const int n = cell / 452, rp = cell - n * 452;
    int y, x;
    if (rp < 114)      { y = 0;   x = rp; }
    else if (rp < 228) { y = 113; x = rp - 114; }
    else {
      const int r2 = rp - 228;                 // 0..223
      x = (r2 & 1) ? 113 : 0;
      y = 1 + (r2 >> 1);                       // 1..112
    }
    const int off = ((n * 114 + y) * 114 + x) * 32 + part * 8;
    *(uint4*)(spk16 + off) = (uint4){0u, 0u, 0u, 0u};
    return;
  }
  if (threadIdx.x >= 64) return;
  const int lane = threadIdx.x;
  const int quad = lane >> 4, nl = lane & 15;
  if (b < 135) {                               // conv2: 9 steps x 15 nsub
    const int s = b / 15, nsub = b - s * 15;   // s = ky*3+kx
    const int ch = nsub * 16 + nl;
    unsigned short* dst = bp2 + (((s * 15 + nsub) * 64 + lane) << 3);
    #pragma unroll
    for (int j = 0; j < 8; ++j) {
      const int ci = quad * 8 + j;
      dst[j] = f2h((ci < 30) ? w2[ch * 270 + ci * 9 + s] : 0.0f);
    }
  } else {                                     // conv1: 8 steps x 2 nsub
    const int bb = b - 135;
    const int s = bb >> 1, nsub = bb & 1;
    const int ch = nsub * 16 + nl;
    unsigned short* dst = bp1 + (((s * 2 + nsub) * 64 + lane) << 3);
    #pragma unroll
    for (int j = 0; j < 8; ++j) {
      int ci, ky;
      bool ok = (ch < 30) && (j < 5);
      if (s < 6)       { ci = s;        ky = quad; }
      else if (s == 6) { ci = quad;     ky = 4;    }
      else             { ci = 4 + quad; ky = 4; ok = ok && (quad < 2); }
      float v = 0.0f;
      if (ok) v = w1[ch * 150 + ci * 25 + ky * 5 + j];
      dst[j] = f2h(v);
    }
  }
}

// ---------------------------------------------------------------------------
// conv1 + fire + maxpool2x2. Pool-interleaved M. M=64/wave. A-frag = one
// 4B-aligned b128 from the parity-matched input copy. grid 2940 x 256.
// Chunked-XCD swizzle (bijective, q=367 r=4). ~14us measured (r3).
// ---------------------------------------------------------------------------
__global__ __launch_bounds__(256) void conv1_mfma(
    const unsigned short* __restrict__ in16,   // ina; inb = ina + IN16_ELEMS
    const unsigned short* __restrict__ bp1,
    unsigned short* __restrict__ spk16)
{
  const int tid = threadIdx.x;
  const int wave = tid >> 6, lane = tid & 63;
  const int quad = lane >> 4, nl = lane & 15;

  // bijective chunked XCD swizzle of 2940 blocks: q=367, r=4
  const int bid = blockIdx.x;
  const int xcd = bid & 7, pos = bid >> 3;
  const int sb = (xcd < 4) ? (xcd * 368 + pos)
                           : (4 * 368 + (xcd - 4) * 367 + pos);
  const int m0 = sb * 256 + wave * 64;

  // parity of x0 is lane-constant: p = nl & 1 (m0, c*16 even)
  const unsigned short* base = in16 + ((nl & 1) ? (IN16_ELEMS - 1) : 0);

  unsigned o_q[4], o_a[4], o_b[4];
  #pragma unroll
  for (int c = 0; c < 4; ++c) {
    const int m = m0 + c * 16 + nl;
    const int sub = m & 3, g = m >> 2;
    const int gx = g % 112, t = g / 112;
    const int gy = t % 112, n = t / 112;
    const int y0 = gy * 2 + (sub >> 1);        // padded coords
    const int x0 = gx * 2 + (sub & 1);
    const unsigned nb = (unsigned)n * 311904u; // 6*51984
    o_q[c] = nb + (unsigned)((y0 + quad) * 228 + x0);
    o_a[c] = nb + (unsigned)quad * 51984u + (unsigned)((y0 + 4) * 228 + x0);
    o_b[c] = nb + (unsigned)(4 + (quad & 1)) * 51984u + (unsigned)((y0 + 4) * 228 + x0);
  }

  f32x4 acc[4][2];
  #pragma unroll
  for (int c = 0; c < 4; ++c) {
    acc[c][0] = (f32x4){0.f, 0.f, 0.f, 0.f};
    acc[c][1] = (f32x4){0.f, 0.f, 0.f, 0.f};
  }

  const half8* bptr = (const half8*)bp1;
  #pragma unroll
  for (int s = 0; s < 8; ++s) {
    const half8 b0 = bptr[(s * 2 + 0) * 64 + lane];
    const half8 b1 = bptr[(s * 2 + 1) * 64 + lane];
    #pragma unroll
    for (int c = 0; c < 4; ++c) {
      const unsigned off = (s < 6) ? (o_q[c] + (unsigned)s * 51984u)
                                   : (s == 6 ? o_a[c] : o_b[c]);
      const half8 A = *(const half8u*)(base + off);
      acc[c][0] = __builtin_amdgcn_mfma_f32_16x16x32_f16(A, b0, acc[c][0], 0, 0, 0);
      acc[c][1] = __builtin_amdgcn_mfma_f32_16x16x32_f16(A, b1, acc[c][1], 0, 0, 0);
    }
  }

  #pragma unroll
  for (int c = 0; c < 4; ++c) {
    const int gq = ((m0 + c * 16) >> 2) + quad;
    const int pgx = gq % 112, tq = gq / 112;
    const int pgy = tq % 112, nq = tq / 112;
    const bool f0 = (acc[c][0][0] > POT1_T) | (acc[c][0][1] > POT1_T) |
                    (acc[c][0][2] > POT1_T) | (acc[c][0][3] > POT1_T);
    const bool f1 = (acc[c][1][0] > POT1_T) | (acc[c][1][1] > POT1_T) |
                    (acc[c][1][2] > POT1_T) | (acc[c][1][3] > POT1_T);
    const size_t o = ((size_t)(nq * 114 + pgy + 1) * 114 + (pgx + 1)) * 32 + nl;
    spk16[o] = f0 ? (unsigned short)0x3C00 : (unsigned short)0;
    // ch>=30 weights are zero-packed -> acc==0 -> stores 0 (inits ch 30/31)
    spk16[o + 16] = f1 ? (unsigned short)0x3C00 : (unsigned short)0;
  }
}

// ---------------------------------------------------------------------------
// conv2 + fire: block = 4 waves x M=64 = 256 rows; N = 5 subtiles (80 ch),
// 3 N-tiles cover 240. B staged in LDS (45 KB). Subtiles in two groups
// (3 then 2). Epilogue: LDS-transpose (4KB/wave, XOR-swizzled) -> full-line
// 1KB nt stores (4 ch x 256B per instruction). grid 2208 x 256,
// sibling-XCD swizzle. LDS total 61KB -> 2 blocks/CU.
// ---------------------------------------------------------------------------
#define C2_NSUB 5
__global__ __launch_bounds__(256, 2) void conv2_mfma(
    const unsigned short* __restrict__ spk16,
    const unsigned short* __restrict__ bp2,
    float* __restrict__ out_spk, float* __restrict__ out_pot)
{
  __shared__ __attribute__((aligned(16))) unsigned short Blds[C2_NSUB * 9 * 64 * 8];
  __shared__ __attribute__((aligned(16))) float Tlds[4 * 1024];  // 4KB/wave

  const int tid = threadIdx.x;

  // sibling-XCD swizzle: gid -> (bx, ntile); 3 siblings of one A region
  // land on the same XCD (gid % 8 equal) within a 24-id window.
  const int gid = blockIdx.x;                  // 0..2207
  const int v = gid / 24, u = gid - v * 24;
  const int bx = v * 8 + (u & 7);              // 0..735
  const int ntile = u >> 3;                    // 0..2
  if (bx >= 735) return;                       // 3 idle blocks (uniform exit)

  // stage 5 subtiles x 9 steps x 64 lanes x 16B = 2880 uint4
  for (int i = tid; i < 2880; i += 256) {
    const int su = i / 576, rem = i - su * 576;    // rem = s*64+lane
    ((uint4*)Blds)[su * 576 + rem] =
        ((const uint4*)bp2)[((rem >> 6) * 15 + ntile * C2_NSUB + su) * 64 + (rem & 63)];
  }
  __syncthreads();

  const int wave = tid >> 6, lane = tid & 63;
  const int quad = lane >> 4, nl = lane & 15;
  const int m0 = bx * 256 + wave * 64;         // per-wave 64-m run, 64-aligned

  const unsigned short* abase[4];
  #pragma unroll
  for (int c = 0; c < 4; ++c) {
    const int m = m0 + c * 16 + nl;
    const int x = m % 112, t = m / 112;
    const int y = t % 112, n = t / 112;
    abase[c] = spk16 + ((size_t)(n * 114 + y) * 114 + x) * 32 + quad * 8;
  }

  // wave's flat-contiguous output run: 12544 = 196*64 -> never crosses n
  const int nr = m0 / 12544;
  const int off_in = m0 - nr * 12544;
  float* tw = Tlds + wave * 1024;              // per-wave transpose buffer

  const half8* blds = (const half8*)Blds;

  #pragma unroll
  for (int g = 0; g < 2; ++g) {
    const int ub = g ? 3 : 0;                  // subtile base of this group
    const int uc = g ? 2 : 3;                  // subtiles in this group

    f32x4 acc[4][3];
    #pragma unroll
    for (int c = 0; c < 4; ++c)
      #pragma unroll
      for (int u2 = 0; u2 < 3; ++u2) acc[c][u2] = (f32x4){0.f, 0.f, 0.f, 0.f};

    #pragma unroll
    for (int s = 0; s < 9; ++s) {              // s = ky*3+kx
      const int ky = s / 3, kx = s - ky * 3;   // compile-time under unroll
      half8 a[4];
      #pragma unroll
      for (int c = 0; c < 4; ++c)
        a[c] = *(const half8*)(abase[c] + (ky * 114 + kx) * 32);
      #pragma unroll
      for (int u2 = 0; u2 < 3; ++u2) {
        if (u2 < uc) {
          const half8 b = blds[((ub + u2) * 9 + s) * 64 + lane];
          #pragma unroll
          for (int c = 0; c < 4; ++c)
            acc[c][u2] = __builtin_amdgcn_mfma_f32_16x16x32_f16(a[c], b, acc[c][u2], 0, 0, 0);
        }
      }
    }

    // ---- LDS-transpose epilogue: full-line stores ----
    // acc[c][u2][rr] @ lane(quad,nl) = pot(m = m0 + (c*4+quad)*4 + rr,
    //                                      ch = chbase + nl).
    // Dump piece p=c*4+quad at XOR'd column (p^nl); reload so the wave's
    // 64 lanes cover 4 channels x 64 consecutive floats (256B, aligned)
    // per store instruction.
    #pragma unroll
    for (int u2 = 0; u2 < 3; ++u2) {
      if (u2 < uc) {
        #pragma unroll
        for (int c = 0; c < 4; ++c) {
          const int col = ((c * 4 + quad) ^ nl) & 15;
          *(f32x4*)(tw + nl * 64 + col * 4) = acc[c][u2];
        }
        __builtin_amdgcn_wave_barrier();
        asm volatile("s_waitcnt lgkmcnt(0)" ::: "memory");
        __builtin_amdgcn_sched_barrier(0);
        #pragma unroll
        for (int gch = 0; gch < 4; ++gch) {
          const int chr = gch * 4 + quad;      // source channel 0..15
          const int col = (nl ^ chr) & 15;
          const f32x4 p4 = *(const f32x4*)(tw + chr * 64 + col * 4);
          const int ch = (ntile * C2_NSUB + ub + u2) * 16 + chr;
          const size_t dst = (size_t)(nr * 240 + ch) * 12544 + off_in + nl * 4;
          f32x4 sp, pt;
          #pragma unroll
          for (int rr = 0; rr < 4; ++rr) {
            const bool f = p4[rr] > POT2_T;
            sp[rr] = f ? 1.0f : 0.0f;
            pt[rr] = f ? p4[rr] : 0.0f;
          }
          __builtin_nontemporal_store(sp, (f32x4*)(out_spk + dst));
          __builtin_nontemporal_store(pt, (f32x4*)(out_pot + dst));
        }
        __builtin_amdgcn_wave_barrier();       // reads done before next dump
        asm volatile("s_waitcnt lgkmcnt(0)" ::: "memory");
      }
    }
    __builtin_amdgcn_sched_barrier(0);
  }
}

// ---------------------------------------------------------------------------
extern "C" void kernel_launch(void* const* d_in, const int* in_sizes, int n_in,
                              void* d_out, int out_size, void* d_ws, size_t ws_size,
                              hipStream_t stream)
{
  const float* in = (const float*)d_in[0];
  const float* w1 = (const float*)d_in[1];
  const float* w2 = (const float*)d_in[2];
  float* out = (float*)d_out;

  unsigned short* spk16 = (unsigned short*)d_ws;
  unsigned short* bp2   = (unsigned short*)((char*)d_ws + BP2_OFF);
  unsigned short* bp1   = (unsigned short*)((char*)d_ws + BP1_OFF);
  unsigned short* ina   = (unsigned short*)((char*)d_ws + IN16_OFF);

  prep<<<PAD_BLOCKS + 151 + RING_BLOCKS, 256, 0, stream>>>(
      in, w1, w2, ina, bp2, bp1, spk16);
  conv1_mfma<<<2940, 256, 0, stream>>>(ina, bp1, spk16);
  conv2_mfma<<<2208, 256, 0, stream>>>(
      spk16, bp2, out, out + (size_t)15 * 240 * 112 * 112);
}